// Round 9
// baseline (119.119 us; speedup 1.0000x reference)
//
#include <hip/hip_runtime.h>
#include <math.h>

#define BQ 128
#define NQ 256
#define SMAX 300
#define SPAD 304
#define CCLS 5
#define CCHG 3
#define TSTR 268          // s_tab row stride (floats), cc-major [15][268]
#define RSTR 12           // s_rows row stride (floats)
#define INFV 3.0e38f

// grid: 768 blocks, interleaved — blk%3==0: pair (256), else ss-partial (512)
#define NMAIN 768

__device__ __forceinline__ float fast_sqrtf(float x) {
    return __builtin_amdgcn_sqrtf(x);
}

// pair-block LDS (floats):
#define P_TAB   0
#define P_COLS  4020
#define P_ROWS  6068
#define P_RED   7604
#define P_PART  9652
#define SMEM_FLOATS 9656

// ws layout (floats):
//   ws_col: [0, 65536)            col-min partials [pairblk 0..255][256]
//   ws_ss : [65536, 65536+512*304) ss col partial sums [ssblk 0..511][304]
#define WS_SS 65536

__global__ __launch_bounds__(512, 2) void main_kernel(
    const int* __restrict__ p_class, const int* __restrict__ p_charge,
    const float* __restrict__ cls_logits, const float* __restrict__ chg_logits,
    const float* __restrict__ p_pos, const float* __restrict__ pf_pos,
    const float* __restrict__ p_mom, const float* __restrict__ pf_mom,
    const float* __restrict__ p_en, const float* __restrict__ pf_en,
    const float* __restrict__ setsizes, float* __restrict__ ws,
    float* __restrict__ out)
{
    __shared__ float smem[SMEM_FLOATS];
    const int t = threadIdx.x;
    const int blk = blockIdx.x;
    const int mod3 = blk % 3;

    if (mod3 == 0) {
        // ---------------- pair block: 128 rows x 256 cols ----------------
        const int pblk = blk / 3;          // 0..255
        const int b  = pblk >> 1;
        const int rh = pblk & 1;
        const int base = b * NQ;
        float* s_tab  = smem + P_TAB;
        float* s_cols = smem + P_COLS;
        float* s_rows = smem + P_ROWS;
        float* s_red  = smem + P_RED;
        float* s_part = smem + P_PART;

        if (t < NQ) {
            // NLL table column t (pflow logits) + pflow col data
            const int gj = base + t;
            const float* cl = cls_logits + (size_t)gj * CCLS;
            float l0=cl[0], l1=cl[1], l2=cl[2], l3=cl[3], l4=cl[4];
            float mx = fmaxf(fmaxf(fmaxf(l0,l1),fmaxf(l2,l3)),l4);
            float lse = mx + __logf(__expf(l0-mx)+__expf(l1-mx)+__expf(l2-mx)+
                                    __expf(l3-mx)+__expf(l4-mx));
            const float* gl = chg_logits + (size_t)gj * CCHG;
            float g0=gl[0], g1=gl[1], g2=gl[2];
            float gmx = fmaxf(fmaxf(g0,g1),g2);
            float glse = gmx + __logf(__expf(g0-gmx)+__expf(g1-gmx)+__expf(g2-gmx));
            float nc[CCLS] = {lse-l0, lse-l1, lse-l2, lse-l3, lse-l4};
            float ng[CCHG] = {glse-g0, glse-g1, glse-g2};
            #pragma unroll
            for (int c = 0; c < CCLS; ++c)
                #pragma unroll
                for (int g = 0; g < CCHG; ++g)
                    s_tab[(c*CCHG+g)*TSTR + t] = nc[c] + ng[g];

            float* cr = &s_cols[t*8];
            cr[0]=pf_pos[gj*3+0]; cr[1]=pf_pos[gj*3+1]; cr[2]=pf_pos[gj*3+2];
            cr[3]=pf_mom[gj*3+0]; cr[4]=pf_mom[gj*3+1]; cr[5]=pf_mom[gj*3+2];
            cr[6]=pf_en[gj];      cr[7]=0.0f;
        } else if (t < NQ + 128) {
            // particle row rr of this half
            const int rr = t - NQ;
            const int gr = base + rh*128 + rr;
            float* rw = &s_rows[rr*RSTR];
            rw[0]=p_pos[gr*3+0]; rw[1]=p_pos[gr*3+1]; rw[2]=p_pos[gr*3+2];
            rw[3]=p_mom[gr*3+0]; rw[4]=p_mom[gr*3+1]; rw[5]=p_mom[gr*3+2];
            rw[6]=p_en[gr];
            rw[7]=__int_as_float(p_class[gr]*CCHG + p_charge[gr]);
        }
        __syncthreads();

        const int tx = t & 31;    // local rows tx + 32r, r<4
        const int ty = t >> 5;    // cols ty*16 + c
        const int c0 = ty * 16;

        float4 ra[4], rb[4];
        int ccr[4];
        #pragma unroll
        for (int r = 0; r < 4; ++r) {
            const int row = tx + 32*r;
            ra[r] = *(const float4*)&s_rows[row*RSTR];
            rb[r] = *(const float4*)&s_rows[row*RSTR + 4];
            ccr[r] = __float_as_int(rb[r].w) * TSTR;
        }
        float cmin[16];
        #pragma unroll
        for (int c = 0; c < 16; ++c) cmin[c] = INFV;
        float rmin[4] = {INFV, INFV, INFV, INFV};

        #pragma unroll 4
        for (int c = 0; c < 16; ++c) {
            const int j = c0 + c;
            const float4 cd0 = *(const float4*)&s_cols[j*8];     // half-wave bcast
            const float4 cd1 = *(const float4*)&s_cols[j*8+4];
            float cm = cmin[c];
            #pragma unroll
            for (int r = 0; r < 4; ++r) {
                float dx=ra[r].x-cd0.x, dy=ra[r].y-cd0.y, dz=ra[r].z-cd0.z;
                float ex=ra[r].w-cd0.w, ey=rb[r].x-cd1.x, ez=rb[r].y-cd1.y;
                float de=rb[r].z-cd1.z;
                float v = s_tab[ccr[r] + j]                      // <=15 rows, bcast
                        + fast_sqrtf(dx*dx + dy*dy + dz*dz)
                        + fast_sqrtf(ex*ex + ey*ey + ez*ez)
                        + de*de;
                rmin[r] = fminf(rmin[r], v);
                cm = fminf(cm, v);
            }
            cmin[c] = cm;
        }

        // col-min partials (this row-half) -> ws
        #pragma unroll 4
        for (int c = 0; c < 16; ++c) {
            float v = cmin[c];
            #pragma unroll
            for (int off = 16; off > 0; off >>= 1)
                v = fminf(v, __shfl_down(v, off, 32));
            if (tx == 0) ws[pblk*NQ + c0 + c] = v;
        }
        // row-min partials over ty -> LDS
        #pragma unroll
        for (int r = 0; r < 4; ++r)
            s_red[ty*128 + tx + 32*r] = rmin[r];
        __syncthreads();

        if (t < 128) {
            float m = s_red[t];
            #pragma unroll
            for (int k = 1; k < 16; ++k) m = fminf(m, s_red[k*128 + t]);
            #pragma unroll
            for (int off = 32; off > 0; off >>= 1) m += __shfl_down(m, off, 64);
            if ((t & 63) == 0) s_part[t >> 6] = m;
        }
        __syncthreads();
        if (t == 0)
            atomicAdd(out, (s_part[0] + s_part[1]) * (1.0f / BQ));

    } else {
        // -------- ss partial block: 64 rows x 300 cols -> ws partial ------
        const int sblk = (blk / 3) * 2 + (mod3 - 1);   // 0..511
        const int b  = sblk >> 2;
        const int ch = sblk & 3;
        if (t < SMAX) {
            const float* p = setsizes + ((size_t)b * NQ + (size_t)ch * 64) * SMAX + t;
            float acc = 0.f;
            #pragma unroll 8
            for (int i = 0; i < 64; ++i) acc += p[(size_t)i * SMAX];
            ws[WS_SS + sblk * SPAD + t] = acc;
        }
    }
}

// ---------------------------------------------------------------------------
// Finisher: 128 blocks x 512. Per batch: (a) combine 2 col-min halves + sum
// (pflow_loss), (b) combine 4 ss partials -> softmax -> NLL (setsize_loss).
// ---------------------------------------------------------------------------
__global__ __launch_bounds__(512) void finish_kernel(
    const float* __restrict__ ws, const int* __restrict__ n_particles,
    float* __restrict__ out)
{
    const int b = blockIdx.x;
    const int t = threadIdx.x;
    __shared__ float s_m[SPAD];
    __shared__ float s_p[8];
    __shared__ float s_one[1];
    const int wave = t >> 6, lane = t & 63;

    // (a) pflow col-min combine + sum
    float v = 0.f;
    if (t < NQ)
        v = fminf(ws[(b*2)*NQ + t], ws[(b*2+1)*NQ + t]);
    #pragma unroll
    for (int off = 32; off > 0; off >>= 1) v += __shfl_down(v, off, 64);
    if (lane == 0 && wave < 4) s_p[wave] = v;
    __syncthreads();
    float colsum = 0.f;
    if (t == 0) colsum = s_p[0] + s_p[1] + s_p[2] + s_p[3];
    __syncthreads();

    // (b) ss combine + softmax + NLL
    float m = -INFV;
    if (t < SMAX) {
        const float* p = ws + WS_SS + (size_t)(b*4) * SPAD + t;
        m = (p[0] + p[SPAD] + p[2*SPAD] + p[3*SPAD]) * (1.0f / NQ);
        s_m[t] = m;
    }
    float wm = m;
    #pragma unroll
    for (int off = 32; off > 0; off >>= 1) wm = fmaxf(wm, __shfl_down(wm, off, 64));
    if (lane == 0 && wave < 5) s_p[wave] = wm;
    __syncthreads();
    if (t == 0)
        s_one[0] = fmaxf(fmaxf(fmaxf(s_p[0], s_p[1]), fmaxf(s_p[2], s_p[3])), s_p[4]);
    __syncthreads();
    const float mx = s_one[0];
    float e = (t < SMAX) ? __expf(m - mx) : 0.f;
    #pragma unroll
    for (int off = 32; off > 0; off >>= 1) e += __shfl_down(e, off, 64);
    __syncthreads();                     // s_p reuse
    if (lane == 0 && wave < 5) s_p[wave] = e;
    __syncthreads();
    if (t == 0) {
        float s = s_p[0] + s_p[1] + s_p[2] + s_p[3] + s_p[4];
        int nb = n_particles[b];
        float loss = -(s_m[nb] - mx - __logf(s));
        atomicAdd(out, (colsum + loss) * (1.0f / BQ));
    }
}

extern "C" void kernel_launch(void* const* d_in, const int* in_sizes, int n_in,
                              void* d_out, int out_size, void* d_ws, size_t ws_size,
                              hipStream_t stream) {
    (void)in_sizes; (void)n_in; (void)ws_size;
    const int*   p_class     = (const int*)d_in[0];
    const int*   p_charge    = (const int*)d_in[1];
    const int*   n_particles = (const int*)d_in[2];
    const float* cls_logits  = (const float*)d_in[3];
    const float* chg_logits  = (const float*)d_in[4];
    const float* p_pos       = (const float*)d_in[5];
    const float* pf_pos      = (const float*)d_in[6];
    const float* p_mom       = (const float*)d_in[7];
    const float* pf_mom      = (const float*)d_in[8];
    const float* p_en        = (const float*)d_in[9];
    const float* pf_en       = (const float*)d_in[10];
    const float* setsizes    = (const float*)d_in[11];
    float* out = (float*)d_out;
    float* ws  = (float*)d_ws;   // uses 864 KB

    (void)hipMemsetAsync(out, 0, sizeof(float) * (size_t)out_size, stream);

    main_kernel<<<NMAIN, 512, 0, stream>>>(
        p_class, p_charge, cls_logits, chg_logits,
        p_pos, pf_pos, p_mom, pf_mom, p_en, pf_en, setsizes, ws, out);

    finish_kernel<<<BQ, 512, 0, stream>>>(ws, n_particles, out);
}

// Round 10
// 113.128 us; speedup vs baseline: 1.0530x; 1.0530x over previous
//
#include <hip/hip_runtime.h>
#include <math.h>

#define BQ 128
#define NQ 256
#define SMAX 300
#define SPAD 304
#define CCLS 5
#define CCHG 3
#define TSTR 268          // s_tab row stride (floats), cc-major [15][268]
#define RSTR 12           // s_rows row stride (floats)
#define INFV 3.0e38f

// grid: 512 blocks — [0,256): pair (b*2+rowhalf), [256,512): ss partial (b*2+half)
#define NPAIR 256
#define NMAIN 512

__device__ __forceinline__ float fast_sqrtf(float x) {
    return __builtin_amdgcn_sqrtf(x);
}

// pair-block LDS (floats):
#define P_TAB   0
#define P_COLS  4020
#define P_ROWS  6068
#define P_RED   7604
#define P_PART  9652
#define SMEM_FLOATS 9656

// ws layout (floats):
//   ws_col: [0, 65536)             col-min partials [pairblk 0..255][256]
//   ws_ss : [65536, 65536+256*304) ss col partial sums [ssblk 0..255][304]
#define WS_SS 65536

__global__ __launch_bounds__(512, 2) void main_kernel(
    const int* __restrict__ p_class, const int* __restrict__ p_charge,
    const float* __restrict__ cls_logits, const float* __restrict__ chg_logits,
    const float* __restrict__ p_pos, const float* __restrict__ pf_pos,
    const float* __restrict__ p_mom, const float* __restrict__ pf_mom,
    const float* __restrict__ p_en, const float* __restrict__ pf_en,
    const float* __restrict__ setsizes, float* __restrict__ ws,
    float* __restrict__ out)
{
    __shared__ float smem[SMEM_FLOATS];
    const int t = threadIdx.x;
    const int blk = blockIdx.x;

    if (blk < NPAIR) {
        // ---------------- pair block: 128 rows x 256 cols ----------------
        const int b  = blk >> 1;
        const int rh = blk & 1;
        const int base = b * NQ;
        float* s_tab  = smem + P_TAB;
        float* s_cols = smem + P_COLS;
        float* s_rows = smem + P_ROWS;
        float* s_red  = smem + P_RED;
        float* s_part = smem + P_PART;

        if (t < NQ) {
            // NLL table column t (pflow logits) + pflow col data
            const int gj = base + t;
            const float* cl = cls_logits + (size_t)gj * CCLS;
            float l0=cl[0], l1=cl[1], l2=cl[2], l3=cl[3], l4=cl[4];
            float mx = fmaxf(fmaxf(fmaxf(l0,l1),fmaxf(l2,l3)),l4);
            float lse = mx + __logf(__expf(l0-mx)+__expf(l1-mx)+__expf(l2-mx)+
                                    __expf(l3-mx)+__expf(l4-mx));
            const float* gl = chg_logits + (size_t)gj * CCHG;
            float g0=gl[0], g1=gl[1], g2=gl[2];
            float gmx = fmaxf(fmaxf(g0,g1),g2);
            float glse = gmx + __logf(__expf(g0-gmx)+__expf(g1-gmx)+__expf(g2-gmx));
            float nc[CCLS] = {lse-l0, lse-l1, lse-l2, lse-l3, lse-l4};
            float ng[CCHG] = {glse-g0, glse-g1, glse-g2};
            #pragma unroll
            for (int c = 0; c < CCLS; ++c)
                #pragma unroll
                for (int g = 0; g < CCHG; ++g)
                    s_tab[(c*CCHG+g)*TSTR + t] = nc[c] + ng[g];

            float* cr = &s_cols[t*8];
            cr[0]=pf_pos[gj*3+0]; cr[1]=pf_pos[gj*3+1]; cr[2]=pf_pos[gj*3+2];
            cr[3]=pf_mom[gj*3+0]; cr[4]=pf_mom[gj*3+1]; cr[5]=pf_mom[gj*3+2];
            cr[6]=pf_en[gj];      cr[7]=0.0f;
        } else if (t < NQ + 128) {
            // particle row rr of this half
            const int rr = t - NQ;
            const int gr = base + rh*128 + rr;
            float* rw = &s_rows[rr*RSTR];
            rw[0]=p_pos[gr*3+0]; rw[1]=p_pos[gr*3+1]; rw[2]=p_pos[gr*3+2];
            rw[3]=p_mom[gr*3+0]; rw[4]=p_mom[gr*3+1]; rw[5]=p_mom[gr*3+2];
            rw[6]=p_en[gr];
            rw[7]=__int_as_float(p_class[gr]*CCHG + p_charge[gr]);
        }
        __syncthreads();

        const int tx = t & 31;    // local rows tx + 32r, r<4
        const int ty = t >> 5;    // cols ty*16 + c
        const int c0 = ty * 16;

        float4 ra[4], rb[4];
        int ccr[4];
        #pragma unroll
        for (int r = 0; r < 4; ++r) {
            const int row = tx + 32*r;
            ra[r] = *(const float4*)&s_rows[row*RSTR];
            rb[r] = *(const float4*)&s_rows[row*RSTR + 4];
            ccr[r] = __float_as_int(rb[r].w) * TSTR;
        }
        float cmin[16];
        #pragma unroll
        for (int c = 0; c < 16; ++c) cmin[c] = INFV;
        float rmin[4] = {INFV, INFV, INFV, INFV};

        #pragma unroll 4
        for (int c = 0; c < 16; ++c) {
            const int j = c0 + c;
            const float4 cd0 = *(const float4*)&s_cols[j*8];     // half-wave bcast
            const float4 cd1 = *(const float4*)&s_cols[j*8+4];
            float cm = cmin[c];
            #pragma unroll
            for (int r = 0; r < 4; ++r) {
                float dx=ra[r].x-cd0.x, dy=ra[r].y-cd0.y, dz=ra[r].z-cd0.z;
                float ex=ra[r].w-cd0.w, ey=rb[r].x-cd1.x, ez=rb[r].y-cd1.y;
                float de=rb[r].z-cd1.z;
                float v = s_tab[ccr[r] + j]                      // <=15 rows, bcast
                        + fast_sqrtf(dx*dx + dy*dy + dz*dz)
                        + fast_sqrtf(ex*ex + ey*ey + ez*ez)
                        + de*de;
                rmin[r] = fminf(rmin[r], v);
                cm = fminf(cm, v);
            }
            cmin[c] = cm;
        }

        // col-min partials (this row-half) -> ws
        #pragma unroll 4
        for (int c = 0; c < 16; ++c) {
            float v = cmin[c];
            #pragma unroll
            for (int off = 16; off > 0; off >>= 1)
                v = fminf(v, __shfl_down(v, off, 32));
            if (tx == 0) ws[blk*NQ + c0 + c] = v;
        }
        // row-min partials over ty -> LDS
        #pragma unroll
        for (int r = 0; r < 4; ++r)
            s_red[ty*128 + tx + 32*r] = rmin[r];
        __syncthreads();

        if (t < 128) {
            float m = s_red[t];
            #pragma unroll
            for (int k = 1; k < 16; ++k) m = fminf(m, s_red[k*128 + t]);
            #pragma unroll
            for (int off = 32; off > 0; off >>= 1) m += __shfl_down(m, off, 64);
            if ((t & 63) == 0) s_part[t >> 6] = m;
        }
        __syncthreads();
        if (t == 0)
            atomicAdd(out, (s_part[0] + s_part[1]) * (1.0f / BQ));

    } else {
        // -------- ss partial block: 128 rows x 300 cols -> ws partial -----
        const int sblk = blk - NPAIR;      // 0..255
        const int b  = sblk >> 1;
        const int h  = sblk & 1;
        if (t < SMAX) {
            const float* p = setsizes + ((size_t)b * NQ + (size_t)h * 128) * SMAX + t;
            float acc = 0.f;
            #pragma unroll 16
            for (int i = 0; i < 128; ++i) acc += p[(size_t)i * SMAX];
            ws[WS_SS + sblk * SPAD + t] = acc;
        }
    }
}

// ---------------------------------------------------------------------------
// Finisher: 128 blocks x 512. Per batch: (a) fmin of 2 col-min halves + sum
// (pflow_loss), (b) sum 2 ss partials -> softmax -> NLL (setsize_loss).
// ---------------------------------------------------------------------------
__global__ __launch_bounds__(512) void finish_kernel(
    const float* __restrict__ ws, const int* __restrict__ n_particles,
    float* __restrict__ out)
{
    const int b = blockIdx.x;
    const int t = threadIdx.x;
    __shared__ float s_m[SPAD];
    __shared__ float s_p[8];
    __shared__ float s_cs[1];
    __shared__ float s_one[1];
    const int wave = t >> 6, lane = t & 63;

    // (a) pflow col-min combine + sum
    float v = 0.f;
    if (t < NQ)
        v = fminf(ws[(b*2)*NQ + t], ws[(b*2+1)*NQ + t]);
    #pragma unroll
    for (int off = 32; off > 0; off >>= 1) v += __shfl_down(v, off, 64);
    if (lane == 0 && wave < 4) s_p[wave] = v;
    __syncthreads();
    if (t == 0) s_cs[0] = s_p[0] + s_p[1] + s_p[2] + s_p[3];
    __syncthreads();

    // (b) ss combine + softmax + NLL
    float m = -INFV;
    if (t < SMAX) {
        const float* p = ws + WS_SS + (size_t)(b*2) * SPAD + t;
        m = (p[0] + p[SPAD]) * (1.0f / NQ);
        s_m[t] = m;
    }
    float wm = m;
    #pragma unroll
    for (int off = 32; off > 0; off >>= 1) wm = fmaxf(wm, __shfl_down(wm, off, 64));
    if (lane == 0 && wave < 5) s_p[wave] = wm;
    __syncthreads();
    if (t == 0)
        s_one[0] = fmaxf(fmaxf(fmaxf(s_p[0], s_p[1]), fmaxf(s_p[2], s_p[3])), s_p[4]);
    __syncthreads();
    const float mx = s_one[0];
    float e = (t < SMAX) ? __expf(m - mx) : 0.f;
    #pragma unroll
    for (int off = 32; off > 0; off >>= 1) e += __shfl_down(e, off, 64);
    __syncthreads();                     // s_p reuse
    if (lane == 0 && wave < 5) s_p[wave] = e;
    __syncthreads();
    if (t == 0) {
        float s = s_p[0] + s_p[1] + s_p[2] + s_p[3] + s_p[4];
        int nb = n_particles[b];
        float loss = -(s_m[nb] - mx - __logf(s));
        atomicAdd(out, (s_cs[0] + loss) * (1.0f / BQ));
    }
}

extern "C" void kernel_launch(void* const* d_in, const int* in_sizes, int n_in,
                              void* d_out, int out_size, void* d_ws, size_t ws_size,
                              hipStream_t stream) {
    (void)in_sizes; (void)n_in; (void)ws_size;
    const int*   p_class     = (const int*)d_in[0];
    const int*   p_charge    = (const int*)d_in[1];
    const int*   n_particles = (const int*)d_in[2];
    const float* cls_logits  = (const float*)d_in[3];
    const float* chg_logits  = (const float*)d_in[4];
    const float* p_pos       = (const float*)d_in[5];
    const float* pf_pos      = (const float*)d_in[6];
    const float* p_mom       = (const float*)d_in[7];
    const float* pf_mom      = (const float*)d_in[8];
    const float* p_en        = (const float*)d_in[9];
    const float* pf_en       = (const float*)d_in[10];
    const float* setsizes    = (const float*)d_in[11];
    float* out = (float*)d_out;
    float* ws  = (float*)d_ws;   // uses ~570 KB

    (void)hipMemsetAsync(out, 0, sizeof(float) * (size_t)out_size, stream);

    main_kernel<<<NMAIN, 512, 0, stream>>>(
        p_class, p_charge, cls_logits, chg_logits,
        p_pos, pf_pos, p_mom, pf_mom, p_en, pf_en, setsizes, ws, out);

    finish_kernel<<<BQ, 512, 0, stream>>>(ws, n_particles, out);
}